// Round 1
// baseline (443.830 us; speedup 1.0000x reference)
//
#include <hip/hip_runtime.h>
#include <stdint.h>

// ---------------------------------------------------------------------------
// NeuralEmbeddingLayer: patchify -> GEMM1(+bias,gelu,x32) -> GEMM2(+bias,+pos)
// B=32 T=512 N=1024 FT=16 FS=32 -> NP=1024, NCH=512, DIN=H=1024, NCLS=1
// Strategy: bf16 MFMA (16x16x32) m97-style 128x128-tile NT GEMMs, fused
// epilogues. ws: patches bf16 [32768][512], g bf16 [32896][1024] (padded),
// W_embed/W_proj bf16 casts. Total ws = 104,071,168 B (~99.3 MiB).
// ---------------------------------------------------------------------------

typedef __attribute__((ext_vector_type(8))) short bf16x8;   // 8 bf16 = 4 VGPRs
typedef __attribute__((ext_vector_type(4))) float f32x4;    // MFMA C/D frag

__device__ __forceinline__ unsigned short f2bf(float f) {
  union { float f; unsigned u; } v; v.f = f;
  const unsigned u = v.u;
  return (unsigned short)((u + 0x7fffu + ((u >> 16) & 1u)) >> 16);  // RNE
}

__device__ __forceinline__ float gelu_exact(float x) {
  return 0.5f * x * (1.0f + erff(x * 0.70710678118654752440f));
}

// async global->LDS, 16B per lane. LDS dest must be wave-uniform base + lane*16.
__device__ __forceinline__ void gl_lds16(const unsigned short* g, unsigned short* l) {
  __builtin_amdgcn_global_load_lds(
      (const __attribute__((address_space(1))) unsigned int*)g,
      (__attribute__((address_space(3))) unsigned int*)l, 16, 0, 0);
}

// --------------------------- prep kernels ----------------------------------

__global__ void cast_f32_bf16(const float* __restrict__ src,
                              unsigned short* __restrict__ dst, int n) {
  const int i = blockIdx.x * 256 + threadIdx.x;
  if (i < n) dst[i] = f2bf(src[i]);
}

// spikes [32][512][1024] f32 -> patches bf16 [32768][512]
// patches[b*1024 + pt*32 + ps][ft*32 + fs] = spikes[b][pt*16+ft][ps*32+fs]
__global__ void patchify(const float* __restrict__ spikes,
                         unsigned short* __restrict__ P) {
  const int idx = blockIdx.x * 256 + threadIdx.x;  // 4,194,304 threads, 4 elems each
  const int m = idx >> 7;
  const int c = (idx & 127) << 2;
  const int b = m >> 10, p = m & 1023;
  const int pt = p >> 5, ps = p & 31;
  const int ft = c >> 5, fs = c & 31;
  const float4 v = *(const float4*)(spikes +
      (size_t)(((b << 9) + pt * 16 + ft) << 10) + ps * 32 + fs);
  ushort4 o;
  o.x = f2bf(v.x); o.y = f2bf(v.y); o.z = f2bf(v.z); o.w = f2bf(v.w);
  *(ushort4*)(P + (size_t)m * 512 + c) = o;
}

// g rows b*1025 = gelu(cls)*32 (cls tokens skip b_embed: concat is post-linear);
// zero the 96 pad rows [32800, 32896).
__global__ void g0_and_pad(const float* __restrict__ cls,
                           unsigned short* __restrict__ G) {
  const int i = blockIdx.x * 256 + threadIdx.x;  // 98304 threads
  G[(size_t)32800 * 1024 + i] = 0;
  if (i < 1024) {
    const unsigned short bv = f2bf(gelu_exact(cls[i]) * 32.0f);
    for (int b = 0; b < 32; ++b) G[(size_t)(b * 1025) * 1024 + i] = bv;
  }
}

// outputs 1,2: mask=ones [32,1025], stamp=arange(1025) broadcast, as f32.
__global__ void mask_stamp(float* __restrict__ out) {
  const int i = blockIdx.x * 256 + threadIdx.x;
  if (i < 32800) {
    out[33587200 + i] = 1.0f;
    out[33587200 + 32800 + i] = (float)(i % 1025);
  }
}

// --------------------------- NT GEMM core ----------------------------------
// C[M,Ncols] = A[M,K] * B[Ncols,K]^T. 128x128 tile, BK=64, 256 thr = 4 waves,
// each wave a 64x64 subtile = 4x4 mfma_f32_16x16x32_bf16 tiles.
// A-frag: m = lane&15, k = (lane>>4)*8 + j   (8 contiguous bf16 -> ds_read_b128)
// B-frag: n = lane&15, k = (lane>>4)*8 + j   (B given as [N][K], same pattern)
// C/D:    n = lane&15, m = (lane>>4)*4 + reg (verified layout, §3)
template <int K, bool GELU_EPI>
__global__ __launch_bounds__(256) void gemm_bt(
    const unsigned short* __restrict__ A, const unsigned short* __restrict__ B,
    const float* __restrict__ bias, unsigned short* __restrict__ Cg,
    float* __restrict__ Cf, const float* __restrict__ pos, int Mvalid) {
  __shared__ __align__(16) unsigned short lsA[128 * 64];
  __shared__ __align__(16) unsigned short lsB[128 * 64];
  const int tid = threadIdx.x;
  const int lane = tid & 63;
  const int w = tid >> 6;
  const int quad = lane >> 4;
  const int l16 = lane & 15;
  const int rowStart = blockIdx.y * 128;
  const int colStart = blockIdx.x * 128;
  const int wm = (w >> 1) * 64;
  const int wn = (w & 1) * 64;

  f32x4 acc[4][4];
  const f32x4 z = {0.f, 0.f, 0.f, 0.f};
#pragma unroll
  for (int i = 0; i < 4; ++i)
#pragma unroll
    for (int j = 0; j < 4; ++j) acc[i][j] = z;

  // staging: linear LDS byte offset = w*4096 + s*1024 + lane*16
  const int sr = w * 32 + (lane >> 3);     // + s*8
  const int kc = (lane & 7) * 8;

  for (int k0 = 0; k0 < K; k0 += 64) {
    __syncthreads();  // prev tile's ds_reads consumed before overwrite
#pragma unroll
    for (int s = 0; s < 4; ++s) {
      const int r = sr + s * 8;
      gl_lds16(A + (size_t)(rowStart + r) * K + (k0 + kc), lsA + r * 64 + kc);
      gl_lds16(B + (size_t)(colStart + r) * K + (k0 + kc), lsB + r * 64 + kc);
    }
    __syncthreads();  // compiler drains vmcnt(0) here -> LDS valid
#pragma unroll
    for (int kk = 0; kk < 64; kk += 32) {
      bf16x8 af[4], bfr[4];
#pragma unroll
      for (int i = 0; i < 4; ++i)
        af[i] = *(const bf16x8*)(lsA + (wm + i * 16 + l16) * 64 + kk + quad * 8);
#pragma unroll
      for (int j = 0; j < 4; ++j)
        bfr[j] = *(const bf16x8*)(lsB + (wn + j * 16 + l16) * 64 + kk + quad * 8);
#pragma unroll
      for (int i = 0; i < 4; ++i)
#pragma unroll
        for (int j = 0; j < 4; ++j)
          acc[i][j] = __builtin_amdgcn_mfma_f32_16x16x32_bf16(af[i], bfr[j],
                                                              acc[i][j], 0, 0, 0);
    }
  }

#pragma unroll
  for (int i = 0; i < 4; ++i) {
    const int rb = rowStart + wm + i * 16 + quad * 4;
#pragma unroll
    for (int j = 0; j < 4; ++j) {
      const int gc = colStart + wn + j * 16 + l16;
      const float bv = bias[gc];
#pragma unroll
      for (int r = 0; r < 4; ++r) {
        const int row = rb + r;
        float v = acc[i][j][r] + bv;
        if (GELU_EPI) {
          // patch row m=b*1024+p -> g row b*1025 + p + 1
          v = gelu_exact(v) * 32.0f;
          const int grow = row + (row >> 10) + 1;
          Cg[(size_t)grow * 1024 + gc] = f2bf(v);
        } else {
          if (row < Mvalid) {
            const int p = row % 1025;  // g row b*1025+p -> out row, pos_table[p]
            Cf[(size_t)row * 1024 + gc] = v + pos[(size_t)p * 1024 + gc];
          }
        }
      }
    }
  }
}

// --------------------------- launcher --------------------------------------

extern "C" void kernel_launch(void* const* d_in, const int* in_sizes, int n_in,
                              void* d_out, int out_size, void* d_ws, size_t ws_size,
                              hipStream_t stream) {
  const float* spikes  = (const float*)d_in[0];
  const float* W_embed = (const float*)d_in[1];
  const float* b_embed = (const float*)d_in[2];
  const float* cls     = (const float*)d_in[3];
  const float* W_proj  = (const float*)d_in[4];
  const float* b_proj  = (const float*)d_in[5];
  const float* pos     = (const float*)d_in[6];
  float* out = (float*)d_out;

  char* ws = (char*)d_ws;
  unsigned short* P  = (unsigned short*)(ws);              // 32768*512  bf16 = 32 MiB
  unsigned short* G  = (unsigned short*)(ws + 33554432);   // 32896*1024 bf16 = 64.25 MiB
  unsigned short* WE = (unsigned short*)(ws + 100925440);  // 1024*512  bf16
  unsigned short* WP = (unsigned short*)(ws + 101974016);  // 1024*1024 bf16
  // end: 104,071,168 bytes

  hipLaunchKernelGGL(cast_f32_bf16, dim3(2048), dim3(256), 0, stream, W_embed, WE, 524288);
  hipLaunchKernelGGL(cast_f32_bf16, dim3(4096), dim3(256), 0, stream, W_proj, WP, 1048576);
  hipLaunchKernelGGL(patchify, dim3(16384), dim3(256), 0, stream, spikes, P);
  hipLaunchKernelGGL(g0_and_pad, dim3(384), dim3(256), 0, stream, cls, G);
  hipLaunchKernelGGL(mask_stamp, dim3(129), dim3(256), 0, stream, out);

  // GEMM1: [32768,512] x [1024,512]^T -> gelu*32 -> g (bf16)
  hipLaunchKernelGGL((gemm_bt<512, true>), dim3(8, 256), dim3(256), 0, stream,
                     P, WE, b_embed, G, (float*)nullptr, (const float*)nullptr, 0);
  // GEMM2: [32896,1024] x [1024,1024]^T -> +b_proj +pos_table -> out (f32)
  hipLaunchKernelGGL((gemm_bt<1024, false>), dim3(8, 257), dim3(256), 0, stream,
                     G, WP, b_proj, (unsigned short*)nullptr, out, pos, 32800);
}

// Round 2
// 426.761 us; speedup vs baseline: 1.0400x; 1.0400x over previous
//
#include <hip/hip_runtime.h>
#include <stdint.h>

// ---------------------------------------------------------------------------
// NeuralEmbeddingLayer: patchify -> GEMM1(+bias,gelu,x32) -> GEMM2(+bias,+pos)
// R2 changes vs R1:
//  (a) XCD-locality grid swizzle: 1-D grid, xcd=L&7 owns a 32-row-block band,
//      iterated row-major so the 8 col-blocks sharing an A-tile are
//      co-resident on ONE XCD (A-tile hits that XCD's L2 once).
//  (b) XOR-swizzled LDS layout: granule (row,slot) holds k-chunk slot^(row&7)
//      -> ds_read_b128 spreads over all 8 bank groups (was 4 groups, 16-way).
// ---------------------------------------------------------------------------

typedef __attribute__((ext_vector_type(8))) short bf16x8;   // 8 bf16 = 4 VGPRs
typedef __attribute__((ext_vector_type(4))) float f32x4;    // MFMA C/D frag

__device__ __forceinline__ unsigned short f2bf(float f) {
  union { float f; unsigned u; } v; v.f = f;
  const unsigned u = v.u;
  return (unsigned short)((u + 0x7fffu + ((u >> 16) & 1u)) >> 16);  // RNE
}

__device__ __forceinline__ float gelu_exact(float x) {
  return 0.5f * x * (1.0f + erff(x * 0.70710678118654752440f));
}

// async global->LDS, 16B per lane. HW writes lds_base(lane0) + lane*16.
__device__ __forceinline__ void gl_lds16(const unsigned short* g, unsigned short* l) {
  __builtin_amdgcn_global_load_lds(
      (const __attribute__((address_space(1))) unsigned int*)g,
      (__attribute__((address_space(3))) unsigned int*)l, 16, 0, 0);
}

// --------------------------- prep kernels ----------------------------------

__global__ void cast_f32_bf16(const float* __restrict__ src,
                              unsigned short* __restrict__ dst, int n) {
  const int i = blockIdx.x * 256 + threadIdx.x;
  if (i < n) dst[i] = f2bf(src[i]);
}

// spikes [32][512][1024] f32 -> patches bf16 [32768][512]
__global__ void patchify(const float* __restrict__ spikes,
                         unsigned short* __restrict__ P) {
  const int idx = blockIdx.x * 256 + threadIdx.x;
  const int m = idx >> 7;
  const int c = (idx & 127) << 2;
  const int b = m >> 10, p = m & 1023;
  const int pt = p >> 5, ps = p & 31;
  const int ft = c >> 5, fs = c & 31;
  const float4 v = *(const float4*)(spikes +
      (size_t)(((b << 9) + pt * 16 + ft) << 10) + ps * 32 + fs);
  ushort4 o;
  o.x = f2bf(v.x); o.y = f2bf(v.y); o.z = f2bf(v.z); o.w = f2bf(v.w);
  *(ushort4*)(P + (size_t)m * 512 + c) = o;
}

// g rows b*1025 = gelu(cls)*32 (cls skips b_embed); zero pad rows [32800,32896)
__global__ void g0_and_pad(const float* __restrict__ cls,
                           unsigned short* __restrict__ G) {
  const int i = blockIdx.x * 256 + threadIdx.x;  // 98304 threads
  G[(size_t)32800 * 1024 + i] = 0;
  if (i < 1024) {
    const unsigned short bv = f2bf(gelu_exact(cls[i]) * 32.0f);
    for (int b = 0; b < 32; ++b) G[(size_t)(b * 1025) * 1024 + i] = bv;
  }
}

__global__ void mask_stamp(float* __restrict__ out) {
  const int i = blockIdx.x * 256 + threadIdx.x;
  if (i < 32800) {
    out[33587200 + i] = 1.0f;
    out[33587200 + 32800 + i] = (float)(i % 1025);
  }
}

// --------------------------- NT GEMM core ----------------------------------
// C[M,N] = A[M,K]*B[N,K]^T. 128x128 tile, BK=64, 4 waves x (4x4) 16x16x32 mfma.
// LDS granule (row, slot) holds global k-chunk (slot ^ (row&7)).
// ROWBLKS: 256 (GEMM1) or 257 (GEMM2, extra row-block round-robined per XCD).
template <int K, bool GELU_EPI, int ROWBLKS>
__global__ __launch_bounds__(256) void gemm_bt(
    const unsigned short* __restrict__ A, const unsigned short* __restrict__ B,
    const float* __restrict__ bias, unsigned short* __restrict__ Cg,
    float* __restrict__ Cf, const float* __restrict__ pos, int Mvalid) {
  __shared__ __align__(16) unsigned short lsA[128 * 64];
  __shared__ __align__(16) unsigned short lsB[128 * 64];
  const int tid = threadIdx.x;
  const int lane = tid & 63;
  const int w = tid >> 6;
  const int quad = lane >> 4;
  const int l16 = lane & 15;

  // XCD-locality swizzle (assumes XCD = linear_block_id % 8 round-robin; if
  // wrong this is a harmless permutation). Each xcd owns rows [xcd*32, +32),
  // iterated row-major so 8 A-sharing col-blocks are concurrent on one XCD.
  const int L = blockIdx.x;
  const int xcd = L & 7;
  const int j = L >> 3;
  int rowBlk, colBlk;
  if (ROWBLKS > 256 && j >= 256) { rowBlk = 256; colBlk = xcd; }
  else { rowBlk = xcd * 32 + (j >> 3); colBlk = j & 7; }
  const int rowStart = rowBlk * 128;
  const int colStart = colBlk * 128;
  const int wm = (w >> 1) * 64;
  const int wn = (w & 1) * 64;

  f32x4 acc[4][4];
  const f32x4 z = {0.f, 0.f, 0.f, 0.f};
#pragma unroll
  for (int i = 0; i < 4; ++i)
#pragma unroll
    for (int j2 = 0; j2 < 4; ++j2) acc[i][j2] = z;

  // staging: granule g = w*256 + s*64 + lane; row=g>>3, slot=g&7,
  // global k-chunk = slot ^ (row&7). LDS elem offset = g*8 (linear in lane).
  const int g0 = w * 256 + lane;

  for (int k0 = 0; k0 < K; k0 += 64) {
    __syncthreads();
#pragma unroll
    for (int s = 0; s < 4; ++s) {
      const int g = g0 + s * 64;
      const int r = g >> 3;
      const int slot = g & 7;
      const int kc = (slot ^ (r & 7)) * 8;
      gl_lds16(A + (size_t)(rowStart + r) * K + (k0 + kc), lsA + r * 64 + slot * 8);
      gl_lds16(B + (size_t)(colStart + r) * K + (k0 + kc), lsB + r * 64 + slot * 8);
    }
    __syncthreads();
#pragma unroll
    for (int kk = 0; kk < 64; kk += 32) {
      bf16x8 af[4], bfr[4];
      const int kcb = (kk >> 3) + quad;          // logical k-chunk 0..7
#pragma unroll
      for (int i = 0; i < 4; ++i) {
        const int r = wm + i * 16 + l16;
        af[i] = *(const bf16x8*)(lsA + r * 64 + (kcb ^ (r & 7)) * 8);
      }
#pragma unroll
      for (int j2 = 0; j2 < 4; ++j2) {
        const int r = wn + j2 * 16 + l16;
        bfr[j2] = *(const bf16x8*)(lsB + r * 64 + (kcb ^ (r & 7)) * 8);
      }
#pragma unroll
      for (int i = 0; i < 4; ++i)
#pragma unroll
        for (int j2 = 0; j2 < 4; ++j2)
          acc[i][j2] = __builtin_amdgcn_mfma_f32_16x16x32_bf16(af[i], bfr[j2],
                                                               acc[i][j2], 0, 0, 0);
    }
  }

#pragma unroll
  for (int i = 0; i < 4; ++i) {
    const int rb = rowStart + wm + i * 16 + quad * 4;
#pragma unroll
    for (int j2 = 0; j2 < 4; ++j2) {
      const int gc = colStart + wn + j2 * 16 + l16;
      const float bv = bias[gc];
#pragma unroll
      for (int r = 0; r < 4; ++r) {
        const int row = rb + r;
        float v = acc[i][j2][r] + bv;
        if (GELU_EPI) {
          v = gelu_exact(v) * 32.0f;
          const int grow = row + (row >> 10) + 1;   // b*1024+p -> b*1025+p+1
          Cg[(size_t)grow * 1024 + gc] = f2bf(v);
        } else {
          if (row < Mvalid) {
            const int p = row % 1025;               // magic-mul, cheap
            Cf[(size_t)row * 1024 + gc] = v + pos[(size_t)p * 1024 + gc];
          }
        }
      }
    }
  }
}

// --------------------------- launcher --------------------------------------

extern "C" void kernel_launch(void* const* d_in, const int* in_sizes, int n_in,
                              void* d_out, int out_size, void* d_ws, size_t ws_size,
                              hipStream_t stream) {
  const float* spikes  = (const float*)d_in[0];
  const float* W_embed = (const float*)d_in[1];
  const float* b_embed = (const float*)d_in[2];
  const float* cls     = (const float*)d_in[3];
  const float* W_proj  = (const float*)d_in[4];
  const float* b_proj  = (const float*)d_in[5];
  const float* pos     = (const float*)d_in[6];
  float* out = (float*)d_out;

  char* ws = (char*)d_ws;
  unsigned short* P  = (unsigned short*)(ws);              // 32 MiB
  unsigned short* G  = (unsigned short*)(ws + 33554432);   // 64.25 MiB
  unsigned short* WE = (unsigned short*)(ws + 100925440);  // 1 MiB
  unsigned short* WP = (unsigned short*)(ws + 101974016);  // 2 MiB

  hipLaunchKernelGGL(cast_f32_bf16, dim3(2048), dim3(256), 0, stream, W_embed, WE, 524288);
  hipLaunchKernelGGL(cast_f32_bf16, dim3(4096), dim3(256), 0, stream, W_proj, WP, 1048576);
  hipLaunchKernelGGL(patchify, dim3(16384), dim3(256), 0, stream, spikes, P);
  hipLaunchKernelGGL(g0_and_pad, dim3(384), dim3(256), 0, stream, cls, G);
  hipLaunchKernelGGL(mask_stamp, dim3(129), dim3(256), 0, stream, out);

  // GEMM1: [32768,512] x [1024,512]^T -> gelu*32 -> G (bf16), 2048 blocks
  hipLaunchKernelGGL((gemm_bt<512, true, 256>), dim3(2048), dim3(256), 0, stream,
                     P, WE, b_embed, G, (float*)nullptr, (const float*)nullptr, 0);
  // GEMM2: [32896,1024] x [1024,1024]^T -> +b_proj +pos -> out (f32), 2056 blocks
  hipLaunchKernelGGL((gemm_bt<1024, false, 257>), dim3(2056), dim3(256), 0, stream,
                     G, WP, b_proj, (unsigned short*)nullptr, out, pos, 32800);
}